// Round 9
// baseline (259.068 us; speedup 1.0000x reference)
//
#include <hip/hip_runtime.h>

#define S_LEN 2048
#define BATCH 2
#define DM 1024
#define NH 16
#define DK 64
#define M_ROWS 4096

typedef __bf16 bf16x8 __attribute__((ext_vector_type(8)));
typedef float f32x4 __attribute__((ext_vector_type(4)));
typedef unsigned int u32;
typedef unsigned short u16;

__device__ __forceinline__ float bf2f(u16 u) {
    union { u32 i; float f; } v;
    v.i = ((u32)u) << 16;
    return v.f;
}

// round-to-nearest-even fp32 -> bf16 (finite)
__device__ __forceinline__ u16 rne16(float f) {
    u32 i = __builtin_bit_cast(u32, f);
    return (u16)((i + 0x7fffu + ((i >> 16) & 1u)) >> 16);
}

// pack two fp32 -> bf16x2 (round-half-up; finite)
__device__ __forceinline__ u32 pk2(float x, float y) {
    u32 a = __builtin_bit_cast(u32, x) + 0x8000u;
    u32 b = __builtin_bit_cast(u32, y) + 0x8000u;
    return (a >> 16) | (b & 0xffff0000u);
}

// async global->LDS, 16B per lane
__device__ __forceinline__ void async16(const void* g, void* l) {
    __builtin_amdgcn_global_load_lds(
        (const __attribute__((address_space(1))) u32*)((unsigned long long)g),
        (__attribute__((address_space(3))) u32*)((u32)(unsigned long long)l),
        16, 0, 0);
}

// ---------------------------------------------------------------------------
// One-shot fp32->bf16 of all 7 tensors (2048 elems / block).
// ---------------------------------------------------------------------------
__global__ __launch_bounds__(256) void cvt_all(
    const float* __restrict__ q, const float* __restrict__ k,
    const float* __restrict__ v, const float* __restrict__ wq,
    const float* __restrict__ wk, const float* __restrict__ wv,
    const float* __restrict__ wo,
    u16* q16, u16* k16, u16* v16, u16* wq16, u16* wk16, u16* wv16, u16* wo16)
{
    const int b = blockIdx.x;
    const float* src; u16* dst; long off;
    if (b < 2048)      { src = q;  dst = q16;  off = (long)b * 2048; }
    else if (b < 4096) { src = k;  dst = k16;  off = (long)(b - 2048) * 2048; }
    else if (b < 6144) { src = v;  dst = v16;  off = (long)(b - 4096) * 2048; }
    else if (b < 6656) { src = wq; dst = wq16; off = (long)(b - 6144) * 2048; }
    else if (b < 7168) { src = wk; dst = wk16; off = (long)(b - 6656) * 2048; }
    else if (b < 7680) { src = wv; dst = wv16; off = (long)(b - 7168) * 2048; }
    else               { src = wo; dst = wo16; off = (long)(b - 7680) * 2048; }
    const long i = off + (long)threadIdx.x * 8;
    const float4 a = *(const float4*)(src + i);
    const float4 c = *(const float4*)(src + i + 4);
    uint4 r;
    r.x = pk2(a.x, a.y); r.y = pk2(a.z, a.w);
    r.z = pk2(c.x, c.y); r.w = pk2(c.z, c.w);
    *(uint4*)(dst + i) = r;
}

// ---------------------------------------------------------------------------
// bf16 GEMM, BMx128 tile, BK=64, K=N=1024. Double-buffered global_load_lds
// (single barrier/iter, 16 iters). Chunk (row,c) -> slot row*8 + (c^(row&7))
// gives uniform bank use for both DMA placement and b128 fragment reads.
// Epilogue via LDS transpose -> coalesced uint4 stores.
// mode 1: [B,H,S,DK]; mode 2: [B,H,DK,S]; mode 3: [M,1024].
// ---------------------------------------------------------------------------
template <int BM>
__global__ __launch_bounds__(256) void gemm_t(
    const u16* __restrict__ A0, const u16* __restrict__ W0,
    const float* __restrict__ bi0, u16* __restrict__ C0, float s0, int md0,
    const u16* __restrict__ A1, const u16* __restrict__ W1,
    const float* __restrict__ bi1, u16* __restrict__ C1, float s1, int md1,
    const u16* __restrict__ A2, const u16* __restrict__ W2,
    const float* __restrict__ bi2, u16* __restrict__ C2, float s2, int md2)
{
    constexpr int IT  = BM / 32;     // i-tiles per wave
    constexpr int ALD = BM / 32;     // A DMA loads per thread per iter
    constexpr int ASZ = BM * 64;     // elems per A buffer
    constexpr int BSZ = 128 * 64;    // elems per B buffer
    __shared__ u16 smem[2 * ASZ + 2 * BSZ];

    const int z = blockIdx.z;
    const u16* A = z == 0 ? A0 : (z == 1 ? A1 : A2);
    const u16* W = z == 0 ? W0 : (z == 1 ? W1 : W2);
    const float* bias = z == 0 ? bi0 : (z == 1 ? bi1 : bi2);
    u16* C = z == 0 ? C0 : (z == 1 ? C1 : C2);
    const float scale = z == 0 ? s0 : (z == 1 ? s1 : s2);
    const int mode = z == 0 ? md0 : (z == 1 ? md1 : md2);

    const int t    = threadIdx.x;
    const int lane = t & 63;
    const int wave = t >> 6;
    const int quad = lane >> 4;
    const int lr   = lane & 15;
    const int wm   = (wave >> 1) * (BM / 2);
    const int wn   = (wave & 1) * 64;
    const int m0   = blockIdx.y * BM;
    const int n0   = blockIdx.x * 128;

    f32x4 acc[IT][4];
#pragma unroll
    for (int i = 0; i < IT; i++)
#pragma unroll
        for (int j = 0; j < 4; j++) acc[i][j] = (f32x4){0.f, 0.f, 0.f, 0.f};

    // DMA sources: lds slot id = t + i*256 -> row id>>3, x id&7, chunk x^(row&7)
    const u16* gA[ALD];
#pragma unroll
    for (int i = 0; i < ALD; i++) {
        const int id = t + i * 256, row = id >> 3, x = id & 7;
        gA[i] = A + (long)(m0 + row) * 1024 + (x ^ (row & 7)) * 8;
    }
    const u16* gB[4];
#pragma unroll
    for (int i = 0; i < 4; i++) {
        const int id = t + i * 256, row = id >> 3, x = id & 7;
        gB[i] = W + (long)(n0 + row) * 1024 + (x ^ (row & 7)) * 8;
    }

    // prologue DMA into buf 0
#pragma unroll
    for (int i = 0; i < ALD; i++) async16(gA[i], smem + (t + i * 256) * 8);
#pragma unroll
    for (int i = 0; i < 4; i++)   async16(gB[i], smem + 2 * ASZ + (t + i * 256) * 8);

    for (int kb = 0; kb < 16; kb++) {
        __syncthreads();  // drains DMA for buf kb&1; all waves done with other
        if (kb < 15) {
            const int k1 = (kb + 1) * 64;
            u16* dA = smem + ((kb + 1) & 1) * ASZ;
            u16* dB = smem + 2 * ASZ + ((kb + 1) & 1) * BSZ;
#pragma unroll
            for (int i = 0; i < ALD; i++) async16(gA[i] + k1, dA + (t + i * 256) * 8);
#pragma unroll
            for (int i = 0; i < 4; i++)   async16(gB[i] + k1, dB + (t + i * 256) * 8);
        }
        const u16* sa = smem + (kb & 1) * ASZ;
        const u16* sb = smem + 2 * ASZ + (kb & 1) * BSZ;
        bf16x8 aF[IT][2], bF[4][2];
#pragma unroll
        for (int i = 0; i < IT; i++)
#pragma unroll
            for (int kk = 0; kk < 2; kk++)
                aF[i][kk] = *(const bf16x8*)&sa[((wm + i * 16 + lr) * 8
                                + ((kk * 4 + quad) ^ (lr & 7))) * 8];
#pragma unroll
        for (int j = 0; j < 4; j++)
#pragma unroll
            for (int kk = 0; kk < 2; kk++)
                bF[j][kk] = *(const bf16x8*)&sb[((wn + j * 16 + lr) * 8
                                + ((kk * 4 + quad) ^ (lr & 7))) * 8];
#pragma unroll
        for (int kk = 0; kk < 2; kk++)
#pragma unroll
            for (int i = 0; i < IT; i++)
#pragma unroll
                for (int j = 0; j < 4; j++)
                    acc[i][j] = __builtin_amdgcn_mfma_f32_16x16x32_bf16(
                        aF[i][kk], bF[j][kk], acc[i][j], 0, 0, 0);
    }

    // ---- coalesced epilogue via LDS (C/D layout: col=lr, row=quad*4+r) ----
    u16* sO = smem;
    const int b_ = m0 >> 11;  // batch index (tile never straddles)

    if constexpr (BM == 64) {
        // mode 3 only: [M,1024] rows. sO [64][136]
        __syncthreads();
#pragma unroll
        for (int i = 0; i < IT; i++)
#pragma unroll
            for (int j = 0; j < 4; j++) {
                const float bvv = bias[n0 + wn + j * 16 + lr];
#pragma unroll
                for (int r = 0; r < 4; r++) {
                    const int gmL = wm + i * 16 + quad * 4 + r;
                    sO[gmL * 136 + wn + j * 16 + lr] =
                        rne16((acc[i][j][r] + bvv) * scale);
                }
            }
        __syncthreads();
#pragma unroll
        for (int i = 0; i < 4; i++) {
            const int c = t + i * 256;
            const int row = c >> 4, c8 = c & 15;
            *(uint4*)(C + (long)(m0 + row) * 1024 + n0 + c8 * 8) =
                *(const uint4*)&sO[row * 136 + c8 * 8];
        }
    } else if (mode == 1) {
        // [B,H,S,DK]; two passes over gm halves. sO [64][136]
#pragma unroll
        for (int pass = 0; pass < 2; pass++) {
            __syncthreads();
            if ((wave >> 1) == pass) {
#pragma unroll
                for (int i = 0; i < IT; i++)
#pragma unroll
                    for (int j = 0; j < 4; j++) {
                        const float bvv = bias[n0 + wn + j * 16 + lr];
#pragma unroll
                        for (int r = 0; r < 4; r++) {
                            const int gmL = i * 16 + quad * 4 + r;  // 0..63
                            sO[gmL * 136 + wn + j * 16 + lr] =
                                rne16((acc[i][j][r] + bvv) * scale);
                        }
                    }
            }
            __syncthreads();
#pragma unroll
            for (int i = 0; i < 4; i++) {
                const int c = t + i * 256;
                const int row = c >> 4, c8 = c & 15;
                const int gm = m0 + pass * 64 + row;
                const int gn = n0 + c8 * 8;
                const long idx = (((long)b_ * NH + (gn >> 6)) * S_LEN
                                  + (gm & (S_LEN - 1))) * DK + (gn & 63);
                *(uint4*)(C + idx) = *(const uint4*)&sO[row * 136 + c8 * 8];
            }
        }
    } else {
        // mode 2: [B,H,DK,S]; two passes over gm halves. sO [128 gn][72]
#pragma unroll
        for (int pass = 0; pass < 2; pass++) {
            __syncthreads();
            if ((wave >> 1) == pass) {
#pragma unroll
                for (int i = 0; i < IT; i++)
#pragma unroll
                    for (int j = 0; j < 4; j++) {
                        const float bvv = bias[n0 + wn + j * 16 + lr];
                        const u16 v0 = rne16((acc[i][j][0] + bvv) * scale);
                        const u16 v1 = rne16((acc[i][j][1] + bvv) * scale);
                        const u16 v2 = rne16((acc[i][j][2] + bvv) * scale);
                        const u16 v3 = rne16((acc[i][j][3] + bvv) * scale);
                        uint2 w;
                        w.x = (u32)v0 | ((u32)v1 << 16);
                        w.y = (u32)v2 | ((u32)v3 << 16);
                        *(uint2*)&sO[(wn + j * 16 + lr) * 72 + i * 16 + quad * 4] = w;
                    }
            }
            __syncthreads();
#pragma unroll
            for (int i = 0; i < 4; i++) {
                const int c = t + i * 256;
                const int row = c >> 3, c8 = c & 7;  // row = gnL 0..127
                const int gn = n0 + row;
                const int s = m0 + pass * 64 + c8 * 8;
                const long idx = (((long)b_ * NH + (gn >> 6)) * DK
                                  + (gn & 63)) * S_LEN + (s & (S_LEN - 1));
                *(uint4*)(C + idx) = *(const uint4*)&sO[row * 72 + c8 * 8];
            }
        }
    }
}

// ---------------------------------------------------------------------------
// Flash attention. Block = 128 q of one (b,h). K DMA double-buffered,
// XOR-swizzled; V frags direct from global V^T; Q pre-scaled.
// sP row stride 136 (>=128) — fixes the round-6..8 row-overlap bug.
// LDS: sK 32KB + sP 34.8KB = 66.8KB -> 2 blocks/CU.
// ---------------------------------------------------------------------------
__global__ __launch_bounds__(256, 2) void attn_flash(
    const u16* __restrict__ Q,
    const u16* __restrict__ K,
    const u16* __restrict__ Vt,
    u16* __restrict__ Out)
{
    __shared__ u16 sK[2][8192];
    __shared__ u16 sP[128 * 136];

    const int t    = threadIdx.x;
    const int lane = t & 63;
    const int wave = t >> 6;
    const int quad = lane >> 4;
    const int lr   = lane & 15;
    const int q0   = blockIdx.x * 128;
    const int bh   = blockIdx.y;

    const long baseQK = (long)bh * S_LEN * DK;
    const long baseV  = (long)bh * DK * S_LEN;

#pragma unroll
    for (int i = 0; i < 4; i++) {
        const int l = t + i * 256;
        const int row = l >> 3, c8 = l & 7;
        *(uint4*)&sP[row * 72 + c8 * 8] =
            *(const uint4*)(Q + baseQK + (long)(q0 + row) * DK + c8 * 8);
    }

    const u16* gK[4];
#pragma unroll
    for (int i = 0; i < 4; i++) {
        const int l = t + i * 256;
        const int h = l >> 9, rem = l & 511;
        const int row = rem >> 2, c = (rem & 3) ^ (row & 3);
        gK[i] = K + baseQK + row * DK + h * 32 + c * 8;
    }
#pragma unroll
    for (int i = 0; i < 4; i++)
        async16(gK[i], &sK[0][(t + i * 256) * 8]);
    __syncthreads();

    bf16x8 qf[2][2];
#pragma unroll
    for (int s = 0; s < 2; s++)
#pragma unroll
        for (int h = 0; h < 2; h++)
            qf[s][h] = *(const bf16x8*)&sP[(s * 64 + wave * 16 + lr) * 72 + h * 32 + quad * 8];

    f32x4 oacc[2][4];
#pragma unroll
    for (int s = 0; s < 2; s++)
#pragma unroll
        for (int nj = 0; nj < 4; nj++) oacc[s][nj] = (f32x4){0.f, 0.f, 0.f, 0.f};
    float m_run[2] = {-1e30f, -1e30f}, l_run[2] = {0.f, 0.f};

    const int sw = quad ^ (lr & 3);

    for (int kb = 0; kb < S_LEN / 128; kb++) {
        const int buf = kb & 1, nb = buf ^ 1;
        __syncthreads();

        uint4 bvr[16];
#pragma unroll
        for (int nj = 0; nj < 4; nj++)
#pragma unroll
            for (int kk = 0; kk < 4; kk++)
                bvr[nj * 4 + kk] = *(const uint4*)(Vt + baseV
                    + (long)(nj * 16 + lr) * S_LEN + kb * 128 + kk * 32 + quad * 8);

        if (kb + 1 < S_LEN / 128) {
#pragma unroll
            for (int i = 0; i < 4; i++)
                async16(gK[i] + (long)(kb + 1) * 128 * DK, &sK[nb][(t + i * 256) * 8]);
        }

        f32x4 sacc[8][2];
#pragma unroll
        for (int mi = 0; mi < 8; mi++) {
            const bf16x8 a0 = *(const bf16x8*)&sK[buf][(((mi * 16 + lr) * 4) + sw) * 8];
            const bf16x8 a1 = *(const bf16x8*)&sK[buf][((512 + (mi * 16 + lr) * 4) + sw) * 8];
            const f32x4 z = (f32x4){0.f, 0.f, 0.f, 0.f};
            sacc[mi][0] = __builtin_amdgcn_mfma_f32_16x16x32_bf16(
                a1, qf[0][1],
                __builtin_amdgcn_mfma_f32_16x16x32_bf16(a0, qf[0][0], z, 0, 0, 0), 0, 0, 0);
            sacc[mi][1] = __builtin_amdgcn_mfma_f32_16x16x32_bf16(
                a1, qf[1][1],
                __builtin_amdgcn_mfma_f32_16x16x32_bf16(a0, qf[1][0], z, 0, 0, 0), 0, 0, 0);
        }

#pragma unroll
        for (int s = 0; s < 2; s++) {
            float mloc = -1e30f;
#pragma unroll
            for (int mi = 0; mi < 8; mi++)
#pragma unroll
                for (int r = 0; r < 4; r++) mloc = fmaxf(mloc, sacc[mi][s][r]);
            mloc = fmaxf(mloc, __shfl_xor(mloc, 16, 64));
            mloc = fmaxf(mloc, __shfl_xor(mloc, 32, 64));
            const float m_new = fmaxf(m_run[s], mloc);
            const float alpha = __builtin_amdgcn_exp2f(m_run[s] - m_new);
            m_run[s] = m_new;

            float psum = 0.f;
#pragma unroll
            for (int mi = 0; mi < 8; mi++)
#pragma unroll
                for (int r = 0; r < 4; r++) {
                    const float p = __builtin_amdgcn_exp2f(sacc[mi][s][r] - m_new);
                    sacc[mi][s][r] = p;
                    psum += p;
                }
            psum += __shfl_xor(psum, 16, 64);
            psum += __shfl_xor(psum, 32, 64);
            l_run[s] = l_run[s] * alpha + psum;

            float ar[4];
#pragma unroll
            for (int r = 0; r < 4; r++) ar[r] = __shfl(alpha, quad * 4 + r, 64);
#pragma unroll
            for (int nj = 0; nj < 4; nj++)
#pragma unroll
                for (int r = 0; r < 4; r++) oacc[s][nj][r] *= ar[r];

            const int prow = s * 64 + wave * 16 + lr;
#pragma unroll
            for (int mi = 0; mi < 8; mi++) {
                uint2 w;
                w.x = pk2(sacc[mi][s][0], sacc[mi][s][1]);
                w.y = pk2(sacc[mi][s][2], sacc[mi][s][3]);
                *(uint2*)&sP[prow * 136 + mi * 16 + quad * 4] = w;
            }
#pragma unroll
            for (int kk = 0; kk < 4; kk++) {
                const bf16x8 pa = *(const bf16x8*)&sP[prow * 136 + kk * 32 + quad * 8];
#pragma unroll
                for (int nj = 0; nj < 4; nj++) {
                    const bf16x8 bb = *(const bf16x8*)&bvr[nj * 4 + kk];
                    oacc[s][nj] = __builtin_amdgcn_mfma_f32_16x16x32_bf16(
                        pa, bb, oacc[s][nj], 0, 0, 0);
                }
            }
        }
    }

    const int b = bh >> 4, h = bh & (NH - 1);
#pragma unroll
    for (int s = 0; s < 2; s++) {
        const float inv = 1.0f / l_run[s];
        float ivr[4];
#pragma unroll
        for (int r = 0; r < 4; r++) ivr[r] = __shfl(inv, quad * 4 + r, 64);
#pragma unroll
        for (int nj = 0; nj < 4; nj++)
#pragma unroll
            for (int r = 0; r < 4; r++) {
                const int qg = q0 + s * 64 + wave * 16 + quad * 4 + r;
                const long oi = ((long)(b * S_LEN + qg)) * DM + h * DK + nj * 16 + lr;
                Out[oi] = rne16(oacc[s][nj][r] * ivr[r]);
            }
    }
}

// ---------------------------------------------------------------------------
// Residual + LayerNorm: out = LN(X + O) * gamma + beta. X fp32, O bf16.
// ---------------------------------------------------------------------------
__global__ __launch_bounds__(256) void ln_res(
    const float* __restrict__ X,
    const u16* __restrict__ O,
    const float* __restrict__ gamma,
    const float* __restrict__ beta,
    float* __restrict__ Out)
{
    __shared__ float sR[8];
    const int row = blockIdx.x;
    const int t = threadIdx.x;
    const int lane = t & 63, wave = t >> 6;
    const long off = (long)row * DM + t * 4;

    const float4 x4 = *(const float4*)(X + off);
    const uint2  uo = *(const uint2*)(O + off);
    float x[4];
    x[0] = x4.x + bf2f((u16)(uo.x & 0xffffu));
    x[1] = x4.y + bf2f((u16)(uo.x >> 16));
    x[2] = x4.z + bf2f((u16)(uo.y & 0xffffu));
    x[3] = x4.w + bf2f((u16)(uo.y >> 16));

    float s  = x[0] + x[1] + x[2] + x[3];
    float ss = x[0] * x[0] + x[1] * x[1] + x[2] * x[2] + x[3] * x[3];
#pragma unroll
    for (int o2 = 32; o2 > 0; o2 >>= 1) {
        s  += __shfl_xor(s, o2, 64);
        ss += __shfl_xor(ss, o2, 64);
    }
    if (lane == 0) { sR[wave] = s; sR[4 + wave] = ss; }
    __syncthreads();
    if (t == 0) {
        sR[0] = sR[0] + sR[1] + sR[2] + sR[3];
        sR[4] = sR[4] + sR[5] + sR[6] + sR[7];
    }
    __syncthreads();
    const float mean = sR[0] * (1.0f / DM);
    const float var  = sR[4] * (1.0f / DM) - mean * mean;
    const float rstd = rsqrtf(var + 1e-5f);

    const float4 g4 = *(const float4*)(gamma + t * 4);
    const float4 b4 = *(const float4*)(beta + t * 4);
    float4 r;
    r.x = (x[0] - mean) * rstd * g4.x + b4.x;
    r.y = (x[1] - mean) * rstd * g4.y + b4.y;
    r.z = (x[2] - mean) * rstd * g4.z + b4.z;
    r.w = (x[3] - mean) * rstd * g4.w + b4.w;
    *(float4*)(Out + off) = r;
}

// ---------------------------------------------------------------------------
// ws (32 MB): [0,8) Q16 -> Ob | [8,16) K16 -> Vtb | [16,18) Wq16 | [18,20)
// Wk16 | [20,22) Wv16 | [22,24) Wo16 | [24,32) Kb.
// d_out (16 MB): [0,8) V16 -> Ab | [8,16) Qb; ln_res overwrites all at end.
// Timeline: cvt -> gemmQKV(z=3) -> attn -> gemmWo -> ln.
// ---------------------------------------------------------------------------
extern "C" void kernel_launch(void* const* d_in, const int* in_sizes, int n_in,
                              void* d_out, int out_size, void* d_ws, size_t ws_size,
                              hipStream_t stream)
{
    (void)in_sizes; (void)n_in; (void)out_size; (void)ws_size;
    const float* queries = (const float*)d_in[0];
    const float* keys    = (const float*)d_in[1];
    const float* values  = (const float*)d_in[2];
    const float* Wq = (const float*)d_in[3];
    const float* bq = (const float*)d_in[4];
    const float* Wk = (const float*)d_in[5];
    const float* bk = (const float*)d_in[6];
    const float* Wv = (const float*)d_in[7];
    const float* bv = (const float*)d_in[8];
    const float* Wo = (const float*)d_in[9];
    const float* bo = (const float*)d_in[10];
    const float* gamma = (const float*)d_in[11];
    const float* beta  = (const float*)d_in[12];

    char* ws = (char*)d_ws;
    const size_t MB = (size_t)1024 * 1024;
    u16* Q16  = (u16*)(ws);
    u16* K16  = (u16*)(ws + 8 * MB);
    u16* Wq16 = (u16*)(ws + 16 * MB);
    u16* Wk16 = (u16*)(ws + 18 * MB);
    u16* Wv16 = (u16*)(ws + 20 * MB);
    u16* Wo16 = (u16*)(ws + 22 * MB);
    u16* Kb   = (u16*)(ws + 24 * MB);
    u16* Ob   = Q16;                              // over Q16 (dead)
    u16* Vtb  = K16;                              // over K16 (dead)
    u16* V16  = (u16*)d_out;                      // d_out[0,8)
    u16* Qb   = (u16*)((char*)d_out + 8 * MB);    // d_out[8,16)
    u16* Ab   = (u16*)d_out;                      // over V16 (dead)

    const float CS = 0.18033688011112042f;  // log2(e)/sqrt(64)

    cvt_all<<<8192, 256, 0, stream>>>(queries, keys, values, Wq, Wk, Wv, Wo,
                                      Q16, K16, V16, Wq16, Wk16, Wv16, Wo16);
    gemm_t<128><<<dim3(8, 32, 3), 256, 0, stream>>>(
        Q16, Wq16, bq, Qb, CS, 1,
        K16, Wk16, bk, Kb, 1.0f, 1,
        V16, Wv16, bv, Vtb, 1.0f, 2);
    attn_flash<<<dim3(S_LEN / 128, BATCH * NH), 256, 0, stream>>>(Qb, Kb, Vtb, Ab);
    gemm_t<64><<<dim3(8, 64, 1), 256, 0, stream>>>(
        Ab, Wo16, bo, Ob, 1.0f, 3,
        Ab, Wo16, bo, Ob, 1.0f, 3,
        Ab, Wo16, bo, Ob, 1.0f, 3);
    ln_res<<<M_ROWS, 256, 0, stream>>>(queries, Ob, gamma, beta, (float*)d_out);
}